// Round 6
// baseline (828.370 us; speedup 1.0000x reference)
//
#include <hip/hip_runtime.h>
#include <hip/hip_bf16.h>

#define DEV __device__ __forceinline__

typedef __attribute__((ext_vector_type(4))) float f32x4;
typedef __attribute__((ext_vector_type(8))) __bf16 bf16x8;
typedef unsigned short u16;

// ---------- constants ----------
#define BB 4
#define TT 4096
#define DD 1024
#define PP 1364
#define MM 16384          // B*T
#define PGROUPS 86        // ceil(1364/16)
#define NPACK 5504        // 86*64
#define PPAD 1408         // padded P stride (16B-aligned rows, K dim of out-GEMM)
#define NCH 64            // scan chunks
#define CHL 64            // chunk length
#define CHAN 5456         // B*P

DEV u16 f2b(float f){
  union { float f; unsigned u; } v; v.f = f;
  unsigned r = v.u + 0x7fffu + ((v.u >> 16) & 1u);
  return (u16)(r >> 16);
}
DEV float b2f(u16 b){
  union { unsigned u; float f; } v; v.u = ((unsigned)b) << 16;
  return v.f;
}
// fp16 storage for scan inputs (f/g/o): 4 more mantissa bits than bf16
DEV u16 f2h(float f){
  _Float16 h = (_Float16)f;
  u16 r; __builtin_memcpy(&r, &h, 2); return r;
}
DEV float h2f(u16 b){
  _Float16 h; __builtin_memcpy(&h, &b, 2); return (float)h;
}
DEV float tanhsafe(float x){
  float ax = fabsf(x);
  float e = __expf(-2.f * ax);
  float t = (1.f - e) / (1.f + e);
  return x < 0.f ? -t : t;
}
DEV float sigm(float x){ return 1.f / (1.f + __expf(-x)); }
DEV float capsig(float z){ return sigm(15.f * tanhsafe(z * (1.f/15.f))); }

DEV void gload16(const void* g, void* l){
  __builtin_amdgcn_global_load_lds((const __attribute__((address_space(1))) void*)g,
                                   (__attribute__((address_space(3))) void*)l, 16, 0, 0);
}

// ---------- weight prep ----------
// conv_w [tap,i,o] fp32 -> WcT [o, tap*1024+i] bf16  (tiled transpose)
__global__ void convw_t(const float* __restrict__ cw, u16* __restrict__ wct){
  __shared__ float s[32][33];
  int i0 = blockIdx.x * 32, o0 = blockIdx.y * 32, tap = blockIdx.z;
  int tx = threadIdx.x, ty = threadIdx.y;
  #pragma unroll
  for (int ph = 0; ph < 4; ++ph){
    int ly = ph * 8 + ty;
    s[ly][tx] = cw[((size_t)(tap * DD + i0 + ly)) * DD + o0 + tx];
  }
  __syncthreads();
  #pragma unroll
  for (int ph = 0; ph < 4; ++ph){
    int ly = ph * 8 + ty;
    wct[((size_t)(o0 + ly)) * 4096 + tap * DD + i0 + tx] = f2b(s[tx][ly]);
  }
}

// pack W_i/f/o/c into Wpack[n,d], n = (p>>4)*64 + gate*16 + (p&15); also zero zbuf
// one float4 per thread: 256 threads x 4 floats = exactly one 1024-elem row.
// (round-3 bug: a j=0..3 loop here wrote 4 rows per block -> cross-block race
// that corrupted ~19% of packed rows at gate boundaries; absmax 0.64)
__global__ void packw(const float* __restrict__ wi, const float* __restrict__ wf,
                      const float* __restrict__ wo, const float* __restrict__ wc,
                      u16* __restrict__ wp, float* __restrict__ zbuf){
  int n = blockIdx.x; int tid = threadIdx.x;
  if (n == 0 && tid < 64) zbuf[tid] = 0.f;
  int pg = n >> 6, rem = n & 63, gate = rem >> 4, pl = rem & 15;
  int p = pg * 16 + pl;
  const float* src = (gate == 0) ? wi : (gate == 1) ? wf : (gate == 2) ? wo : wc;
  u16* dst = wp + (size_t)n * DD;
  if (p < PP){
    float4 v = ((const float4*)(src + (size_t)p * DD))[tid];
    ((ushort4*)dst)[tid] = make_ushort4(f2b(v.x), f2b(v.y), f2b(v.z), f2b(v.w));
  } else {
    ((ushort4*)dst)[tid] = make_ushort4(0, 0, 0, 0);
  }
}

// W_out [d, p] fp32 -> WoutB [d, PPAD] bf16, zero pad
__global__ void packwout(const float* __restrict__ wout, u16* __restrict__ wob){
  int dn = blockIdx.x, tid = threadIdx.x;
  u16* dst = wob + (size_t)dn * PPAD;
  const float* src = wout + (size_t)dn * PP;
  for (int idx = tid; idx < PPAD; idx += 256)
    dst[idx] = (idx < PP) ? f2b(src[idx]) : (u16)0;
}

// ---------- RMSNorm: x fp32 -> xn bf16 ----------
__global__ void rmsnorm(const float* __restrict__ x, const float* __restrict__ w,
                        u16* __restrict__ xn){
  int m = blockIdx.x; int tid = threadIdx.x;
  const float4* xv = (const float4*)(x + (size_t)m * DD);
  float4 v = xv[tid];
  float s = v.x*v.x + v.y*v.y + v.z*v.z + v.w*v.w;
  #pragma unroll
  for (int off = 32; off > 0; off >>= 1) s += __shfl_down(s, off);
  __shared__ float red[4];
  if ((tid & 63) == 0) red[tid >> 6] = s;
  __syncthreads();
  float tot = red[0] + red[1] + red[2] + red[3];
  float r = rsqrtf(tot * (1.f / (float)DD) + 1e-5f);
  float4 wq = ((const float4*)w)[tid];
  ushort4 o = make_ushort4(f2b(v.x * r * wq.x), f2b(v.y * r * wq.y),
                           f2b(v.z * r * wq.z), f2b(v.w * r * wq.w));
  ((ushort4*)(xn + (size_t)m * DD))[tid] = o;
}

// ---------- GEMM C = A @ Bt^T, 128x128 tile, 4 waves, bf16 MFMA ----------
// V=0: conv (A row-gather by tap, out xc bf16)
// V=1: gates (epilogue: activations -> fb/gb (stride PP) + ob (stride PPAD), fp16)
// V=2: out   (epilogue: += X, fp32 to Cout)
template<int V, int KK, int LDA, int LDB>
__global__ __launch_bounds__(256)
void gemm_bt(const u16* __restrict__ A, const u16* __restrict__ Bt,
             void* __restrict__ Cout, const float* __restrict__ X,
             const u16* __restrict__ zsrc,
             u16* __restrict__ fb, u16* __restrict__ gb, u16* __restrict__ ob){
  __shared__ u16 As[128 * 64];
  __shared__ u16 Bs[128 * 64];
  const int tid = threadIdx.x;
  const int wid = tid >> 6, lane = tid & 63;
  const int l15 = lane & 15, l4 = lane >> 4;
  const int m0 = blockIdx.x * 128, n0 = blockIdx.y * 128;
  const int wr = wid >> 1, wc = wid & 1;
  f32x4 acc[4][4];
  #pragma unroll
  for (int i = 0; i < 4; ++i)
    #pragma unroll
    for (int j = 0; j < 4; ++j)
      acc[i][j] = (f32x4){0.f, 0.f, 0.f, 0.f};

  const int srow = tid >> 3;           // 0..31 within 32-row chunk
  const int colb = (tid & 7) * 8;      // element col within 64
  constexpr int NK = KK / 64;

  #pragma unroll 1
  for (int ks = 0; ks < NK; ++ks){
    const int k0 = ks * 64;
    // stage A
    #pragma unroll
    for (int q = 0; q < 4; ++q){
      int row = q * 32 + srow;
      const u16* src;
      if constexpr (V == 0){
        int arow = m0 + row;
        int tap = k0 >> 10;
        int t = arow & (TT - 1);
        if (t + tap - 3 >= 0)
          src = A + (size_t)(arow + tap - 3) * 1024 + (k0 & 1023) + colb;
        else
          src = zsrc;
      } else {
        src = A + (size_t)(m0 + row) * LDA + k0 + colb;
      }
      gload16(src, &As[q * 2048 + wid * 512]);
    }
    // stage B
    #pragma unroll
    for (int q = 0; q < 4; ++q){
      int row = q * 32 + srow;
      const u16* src = Bt + (size_t)(n0 + row) * LDB + k0 + colb;
      gload16(src, &Bs[q * 2048 + wid * 512]);
    }
    __syncthreads();
    #pragma unroll
    for (int kk = 0; kk < 64; kk += 32){
      bf16x8 af[4], bfr[4];
      #pragma unroll
      for (int i = 0; i < 4; ++i)
        af[i] = *(const bf16x8*)&As[(wr * 64 + i * 16 + l15) * 64 + kk + l4 * 8];
      #pragma unroll
      for (int i = 0; i < 4; ++i)
        bfr[i] = *(const bf16x8*)&Bs[(wc * 64 + i * 16 + l15) * 64 + kk + l4 * 8];
      #pragma unroll
      for (int i = 0; i < 4; ++i)
        #pragma unroll
        for (int j = 0; j < 4; ++j)
          acc[i][j] = __builtin_amdgcn_mfma_f32_16x16x32_bf16(af[i], bfr[j], acc[i][j], 0, 0, 0);
    }
    __syncthreads();
  }

  if constexpr (V == 0){
    u16* C = (u16*)Cout;
    #pragma unroll
    for (int mi = 0; mi < 4; ++mi)
      #pragma unroll
      for (int ni = 0; ni < 4; ++ni)
        #pragma unroll
        for (int r = 0; r < 4; ++r){
          int m = m0 + wr * 64 + mi * 16 + l4 * 4 + r;
          int n = n0 + wc * 64 + ni * 16 + l15;
          C[(size_t)m * DD + n] = f2b(acc[mi][ni][r]);
        }
  } else if constexpr (V == 1){
    int pg = blockIdx.y * 2 + wc;
    int p = pg * 16 + l15;
    if (p < PP){
      #pragma unroll
      for (int mi = 0; mi < 4; ++mi)
        #pragma unroll
        for (int r = 0; r < 4; ++r){
          int m = m0 + wr * 64 + mi * 16 + l4 * 4 + r;
          float zi = acc[mi][0][r], zf = acc[mi][1][r];
          float zo = acc[mi][2][r], zc = acc[mi][3][r];
          float fv = capsig(zf);
          float gv = capsig(zi) * tanhsafe(zc);
          float ov = capsig(zo);
          fb[(size_t)m * PP + p] = f2h(fv);
          gb[(size_t)m * PP + p] = f2h(gv);
          ob[(size_t)m * PPAD + p] = f2h(ov);
        }
    }
  } else {
    float* C = (float*)Cout;
    #pragma unroll
    for (int mi = 0; mi < 4; ++mi)
      #pragma unroll
      for (int ni = 0; ni < 4; ++ni)
        #pragma unroll
        for (int r = 0; r < 4; ++r){
          int m = m0 + wr * 64 + mi * 16 + l4 * 4 + r;
          int n = n0 + wc * 64 + ni * 16 + l15;
          size_t off = (size_t)m * DD + n;
          C[off] = X[off] + acc[mi][ni][r];
        }
  }
}

// ---------- scan pass 1: per-chunk (prod f, scan-from-0 result) ----------
__global__ void scan1(const u16* __restrict__ fbuf, const u16* __restrict__ gbuf,
                      float* __restrict__ apass, float* __restrict__ spass){
  int p = blockIdx.x * 256 + threadIdx.x;
  if (p >= PP) return;
  int c = blockIdx.y, b = blockIdx.z;
  size_t base = ((size_t)(b * TT + c * CHL)) * PP + p;
  float a = 1.f, h = 0.f;
  #pragma unroll 8
  for (int j = 0; j < CHL; ++j){
    float f = h2f(fbuf[base]);
    float g = h2f(gbuf[base]);
    a *= f;
    h = f * h + g;
    base += PP;
  }
  int ch = b * PP + p;
  apass[c * CHAN + ch] = a;
  spass[c * CHAN + ch] = h;
}

// ---------- scan pass 2: chunk prefix per channel + h_last ----------
__global__ void scan_mid(const float* __restrict__ hidden, const float* __restrict__ apass,
                         const float* __restrict__ spass, float* __restrict__ hstart,
                         float* __restrict__ hlast){
  int ch = blockIdx.x * 256 + threadIdx.x;
  if (ch >= CHAN) return;
  float h = hidden[ch];
  #pragma unroll 4
  for (int c = 0; c < NCH; ++c){
    hstart[c * CHAN + ch] = h;
    h = apass[c * CHAN + ch] * h + spass[c * CHAN + ch];
  }
  hlast[ch] = h;
}

// ---------- scan pass 3: replay with correct h0, overwrite o (fp16, stride PPAD)
// with y = o*tanh(h) in bf16 in place; zero the pad columns p in [PP, PPAD) ----------
__global__ void scan3(const u16* __restrict__ fbuf, const u16* __restrict__ gbuf,
                      u16* __restrict__ oy, const float* __restrict__ hstart){
  int p = blockIdx.x * 256 + threadIdx.x;
  if (p >= PPAD) return;
  int c = blockIdx.y, b = blockIdx.z;
  size_t ybase = ((size_t)(b * TT + c * CHL)) * PPAD + p;
  if (p >= PP){
    for (int j = 0; j < CHL; ++j){ oy[ybase] = 0; ybase += PPAD; }
    return;
  }
  int ch = b * PP + p;
  float h = hstart[c * CHAN + ch];
  size_t base = ((size_t)(b * TT + c * CHL)) * PP + p;
  #pragma unroll 4
  for (int j = 0; j < CHL; ++j){
    float f = h2f(fbuf[base]);
    float g = h2f(gbuf[base]);
    float o = h2f(oy[ybase]);
    h = f * h + g;
    oy[ybase] = f2b(o * tanhsafe(h));   // y stored bf16 for the out-GEMM
    base += PP; ybase += PPAD;
  }
}

// ---------- launch ----------
extern "C" void kernel_launch(void* const* d_in, const int* in_sizes, int n_in,
                              void* d_out, int out_size, void* d_ws, size_t ws_size,
                              hipStream_t stream){
  const float* x    = (const float*)d_in[0];
  const float* hid  = (const float*)d_in[1];
  const float* rw   = (const float*)d_in[2];
  const float* cw   = (const float*)d_in[3];
  const float* wi   = (const float*)d_in[4];
  const float* wf   = (const float*)d_in[5];
  const float* wo   = (const float*)d_in[6];
  const float* wc   = (const float*)d_in[7];
  const float* wout = (const float*)d_in[8];

  char* ws = (char*)d_ws;
  size_t off = 0;
  auto carve = [&](size_t bytes) -> char* {
    char* p = ws + off;
    off += (bytes + 255) & ~(size_t)255;
    return p;
  };
  // total carved: ~218.8 MiB
  float* zbuf  = (float*)carve(256);
  u16* xn      = (u16*)carve((size_t)MM * DD * 2);      // 32 MiB
  u16* xc      = (u16*)carve((size_t)MM * DD * 2);      // 32 MiB
  u16* wct     = (u16*)carve((size_t)DD * 4096 * 2);    // 8 MiB
  u16* wpack   = (u16*)carve((size_t)NPACK * DD * 2);   // 10.75 MiB
  u16* wob     = (u16*)carve((size_t)DD * PPAD * 2);    // 2.75 MiB
  u16* fbuf    = (u16*)carve((size_t)MM * PP * 2);      // 42.6 MiB (fp16)
  u16* gbuf    = (u16*)carve((size_t)MM * PP * 2);      // 42.6 MiB (fp16)
  u16* obuf    = (u16*)carve((size_t)MM * PPAD * 2);    // 44 MiB (fp16 o, then bf16 y)
  float* apass = (float*)carve((size_t)NCH * CHAN * 4); // 1.33 MiB
  float* spass = (float*)carve((size_t)NCH * CHAN * 4);
  float* hstart= (float*)carve((size_t)NCH * CHAN * 4);

  float* outp  = (float*)d_out;
  float* hlast = outp + (size_t)MM * DD;

  convw_t<<<dim3(32, 32, 4), dim3(32, 8), 0, stream>>>(cw, wct);
  packw<<<NPACK, 256, 0, stream>>>(wi, wf, wo, wc, wpack, zbuf);
  packwout<<<DD, 256, 0, stream>>>(wout, wob);
  rmsnorm<<<MM, 256, 0, stream>>>(x, rw, xn);

  gemm_bt<0, 4096, 1024, 4096><<<dim3(128, 8), 256, 0, stream>>>(
      xn, wct, xc, nullptr, (const u16*)zbuf, nullptr, nullptr, nullptr);

  gemm_bt<1, 1024, 1024, 1024><<<dim3(128, 43), 256, 0, stream>>>(
      xc, wpack, nullptr, nullptr, (const u16*)zbuf, fbuf, gbuf, obuf);

  scan1<<<dim3(6, NCH, BB), 256, 0, stream>>>(fbuf, gbuf, apass, spass);
  scan_mid<<<22, 256, 0, stream>>>(hid, apass, spass, hstart, hlast);
  scan3<<<dim3(6, NCH, BB), 256, 0, stream>>>(fbuf, gbuf, obuf, hstart);

  gemm_bt<2, 1408, 1408, 1408><<<dim3(128, 8), 256, 0, stream>>>(
      obuf, wob, d_out, x, (const u16*)zbuf, nullptr, nullptr, nullptr);
}